// Round 16
// baseline (804.485 us; speedup 1.0000x reference)
//
#include <hip/hip_runtime.h>

typedef _Float16 half8 __attribute__((ext_vector_type(8)));
typedef _Float16 half4_t __attribute__((ext_vector_type(4)));
typedef float f32x4 __attribute__((ext_vector_type(4)));

#define NBATCH 2048
#define NA 64
#define SA 128
#define HID 256

// LDS halves: X 8192 (16KB) | R0 16384 (32KB) | ATT 8192 (16KB) = 65536 B
// ATT frags 0..7: attn A-frags; frags 8..15: per-wave q double-buffer slots.
#define OFF_X 0
#define OFF_R0 8192
#define OFF_ATT (8192 + 16384)
#define SMEM_BYTES ((8192 + 16384 + 8192) * 2)

// packed fp16 weight offsets (halves) inside d_ws
#define W_ENC1 0
#define W_ENC2 (W_ENC1 + 128 * 256)
#define W_ATTN (W_ENC2 + 256 * 256)
#define W_GC1 (W_ATTN + 256 * 256)
#define W_NN1 (W_GC1 + 128 * 256)
#define W_GC2 (W_NN1 + 128 * 256)
#define W_NN2 (W_GC2 + 256 * 256)

#define MFMA(a, b, cacc) __builtin_amdgcn_mfma_f32_16x16x32_f16((a), (b), (cacc), 0, 0, 0)

// lgkmcnt-only barrier (keeps global weight prefetch alive across it).
#define BAR()                                            \
  do {                                                   \
    asm volatile("s_waitcnt lgkmcnt(0)" ::: "memory");   \
    __builtin_amdgcn_s_barrier();                        \
  } while (0)

// One launch packs all 7 weights into MFMA B-fragment order fp16.
// dst[((kt*16+nt)*64+lane)*8 + j] = W[kt*32 + (lane>>4)*8 + j][nt*16 + (lane&15)]
__global__ void pack_all(const float* __restrict__ e1, const float* __restrict__ e2,
                         const float* __restrict__ aw, const float* __restrict__ g1,
                         const float* __restrict__ n1, const float* __restrict__ g2,
                         const float* __restrict__ n2, _Float16* __restrict__ dst) {
  int b = (int)blockIdx.x;
  const float* src;
  int off;
  if (b < 16) { src = e1; off = W_ENC1; }
  else if (b < 48) { src = e2; off = W_ENC2; b -= 16; }
  else if (b < 80) { src = aw; off = W_ATTN; b -= 48; }
  else if (b < 96) { src = g1; off = W_GC1; b -= 80; }
  else if (b < 112) { src = n1; off = W_NN1; b -= 96; }
  else if (b < 144) { src = g2; off = W_GC2; b -= 112; }
  else { src = n2; off = W_NN2; b -= 144; }
  int t = b * 256 + (int)threadIdx.x;
  int lane = t & 63, frag = t >> 6;
  int nt = frag & 15, kt = frag >> 4;
  int g = lane >> 4, c = lane & 15;
  half8 h;
#pragma unroll
  for (int j = 0; j < 8; ++j)
    h[j] = (_Float16)src[(size_t)(kt * 32 + g * 8 + j) * 256 + nt * 16 + c];
  *(half8*)(dst + off + (size_t)t * 8) = h;
}

__global__ __launch_bounds__(256, 2) void dicg_main(
    const float* __restrict__ x, const float* __restrict__ b_enc1,
    const float* __restrict__ b_enc2, const float* __restrict__ b_gc1,
    const float* __restrict__ b_nn1, const float* __restrict__ b_gc2,
    const float* __restrict__ b_nn2, const _Float16* __restrict__ wp,
    float* __restrict__ out, float* __restrict__ attn_out) {
  extern __shared__ _Float16 sm[];
  _Float16* X = sm + OFF_X;        // x fp16 A-frags (read P1[it>0], P5)
  _Float16* R0 = sm + OFF_R0;      // h1 -> emb -> xg1 -> feat(sigma) -> fg2
  _Float16* ATTp = sm + OFF_ATT;   // frags 0..7: attn A-frags; 8..15: q dbuf

  const int tid = (int)threadIdx.x;
  const int wv = tid >> 6;   // wave 0..3 (owns output cols 64*wv..+63)
  const int lane = tid & 63;
  const int g = lane >> 4;   // 0..3
  const int c = lane & 15;   // 0..15
  const int bb0 = (int)blockIdx.x * 2;
  const float* xb;  // set per iteration

  // ---- fragment-linear LDS loads (conflict-free: lane*16B contiguous) ----
  auto ldA = [&](const _Float16* p, int kt, int rt) -> half8 {
    return *(const half8*)(p + (kt * 4 + rt) * 512 + lane * 8);
  };
  auto ldB = [&](const _Float16* p, int kt, int ct) -> half8 {
    return *(const half8*)(p + (kt * 16 + ct) * 512 + lane * 8);
  };
  // feat A-frag (kt,rt) lives at sigma slot (kt&1)*16 + 4*(kt>>1) + rt
  auto ldFeat = [&](int kt, int rt) -> half8 {
    return *(const half8*)(R0 + ((kt & 1) * 16 + 4 * (kt >> 1) + rt) * 512 + lane * 8);
  };
  auto wfrag = [&](const _Float16* wb, int kt, int ntg) -> half8 {
    return *(const half8*)(wb + ((size_t)(kt * 16 + ntg) * 64 + lane) * 8);
  };
  auto xfrag = [&](const float* xp, int r0, int k0) -> half8 {
    const float* p = xp + (r0 + c) * SA + k0 + g * 8;
    f32x4 u = *(const f32x4*)p;
    f32x4 v = *(const f32x4*)(p + 4);
    half8 h;
    h[0] = (_Float16)u[0]; h[1] = (_Float16)u[1];
    h[2] = (_Float16)u[2]; h[3] = (_Float16)u[3];
    h[4] = (_Float16)v[0]; h[5] = (_Float16)v[1];
    h[6] = (_Float16)v[2]; h[7] = (_Float16)v[3];
    return h;
  };

  // ---- packed-LDS stores ----
  // transposed-GEMM epilogue store into A-frag layout (h1/emb producers):
  // lane holds D[hid k0=64wv+16nt+4g+r][agent 16rt+c]; 4 r-values k-contiguous.
  auto stT = [&](int nt, int rt, half4_t hv) {
    int fi = (2 * wv + (nt >> 1)) * 4 + rt;
    int lanep = (2 * (nt & 1) + (g >> 1)) * 16 + c;
    *(half4_t*)(R0 + fi * 512 + lanep * 8 + 4 * (g & 1)) = hv;
  };
  // B-packed store, vectorized: 4 consecutive halves per (rt,nt)
  auto ep_storeB = [&](f32x4(&acc)[4][4], const float* bias) {
#pragma unroll
    for (int nt = 0; nt < 4; ++nt) {
      float bv = bias[64 * wv + 16 * nt + c];
#pragma unroll
      for (int rt = 0; rt < 4; ++rt) {
        half4_t h;
#pragma unroll
        for (int r = 0; r < 4; ++r) h[r] = (_Float16)(acc[rt][nt][r] + bv);
        int fi = (rt >> 1) * 16 + 4 * wv + nt;
        int lanep = (2 * (rt & 1) + (g >> 1)) * 16 + c;
        *(half4_t*)(R0 + fi * 512 + lanep * 8 + 4 * (g & 1)) = h;
      }
    }
  };
  // transposed-tile feat store -> sigma A-frag slot (half4)
  auto stFeatT = [&](int nt, int rt, half4_t hv) {
    int fi = (nt >> 1) * 16 + 4 * wv + rt;
    int lanep = (2 * (nt & 1) + (g >> 1)) * 16 + c;
    *(half4_t*)(R0 + fi * 512 + lanep * 8 + 4 * (g & 1)) = hv;
  };
  // q chunk C-layout -> per-wave double-buffered B-frag scratch (frags 8..15)
  auto stQ = [&](const f32x4(&q2)[2], int s) {
    _Float16* base = ATTp + (8 + 2 * wv + s) * 512;
#pragma unroll
    for (int nt2 = 0; nt2 < 2; ++nt2)
#pragma unroll
      for (int r = 0; r < 4; ++r)
        base[((2 * nt2 + (c >> 3)) * 16 + 4 * g + r) * 8 + (c & 7)] = (_Float16)q2[nt2][r];
  };

  // cross-barrier weight prefetch registers
  half8 pf2[4][4];               // P2: W_ENC2 kt=0..3
  half8 pfq[8][2];               // P3: W_ATTN k2=0..7, cols 0,1 (full q-tile 0)
  half8 pf5g[2][4], pf5n[2][4];  // P5: W_GC1 / W_NN1 kt=0,1
  half8 pf7n[3][4], pf7g[3][4];  // P7: W_NN2 / W_GC2 kt=0,1 (P5) + kt=2 (P6)

  for (int it = 0; it < 2; ++it) {
    const int bb = bb0 + it;
    xb = x + (size_t)bb * (NA * SA);
    if (it) BAR();  // order prev P8 R0-reads before this iteration's P1 R0-writes

    // ===== P1: h1T = W1T·xT (+bias, relu) -> R0 A-frag layout; stage X (it 0) =====
    {
      f32x4 acc[4][4]{};  // [nt(hid)][rt(agent)]
#pragma unroll
      for (int kt = 0; kt < 4; ++kt) {
        half8 af[4], wf[4];
#pragma unroll
        for (int rt = 0; rt < 4; ++rt)
          af[rt] = (it == 0) ? xfrag(xb, 16 * rt, kt * 32) : ldA(X, kt, rt);
#pragma unroll
        for (int nt = 0; nt < 4; ++nt) wf[nt] = wfrag(wp + W_ENC1, kt, 4 * wv + nt);
        if (it == 0 && kt == wv) {  // each wave stages one kt of x
#pragma unroll
          for (int rt = 0; rt < 4; ++rt)
            *(half8*)(X + (kt * 4 + rt) * 512 + lane * 8) = af[rt];
        }
#pragma unroll
        for (int nt = 0; nt < 4; ++nt)
#pragma unroll
          for (int rt = 0; rt < 4; ++rt) acc[nt][rt] = MFMA(wf[nt], af[rt], acc[nt][rt]);
      }
      // prefetch P2's first four K-tiles of W_ENC2 (consumed after B1)
#pragma unroll
      for (int s = 0; s < 4; ++s)
#pragma unroll
        for (int nt = 0; nt < 4; ++nt) pf2[s][nt] = wfrag(wp + W_ENC2, s, 4 * wv + nt);
#pragma unroll
      for (int nt = 0; nt < 4; ++nt) {
        f32x4 bv4 = *(const f32x4*)(b_enc1 + 64 * wv + 16 * nt + 4 * g);
#pragma unroll
        for (int rt = 0; rt < 4; ++rt) {
          half4_t hv;
#pragma unroll
          for (int r = 0; r < 4; ++r) hv[r] = (_Float16)fmaxf(acc[nt][rt][r] + bv4[r], 0.f);
          stT(nt, rt, hv);
        }
      }
    }
    BAR();  // B1: h1 visible
    // ===== P2: embT = W2T·h1T (+bias, relu), in-place over R0 =====
    {
      f32x4 acc[4][4]{};  // [mt(hid)][rt(agent)]
#pragma unroll
      for (int kt = 0; kt < 8; ++kt) {
        half8 hf[4], wf[4];
#pragma unroll
        for (int rt = 0; rt < 4; ++rt) hf[rt] = ldA(R0, kt, rt);
#pragma unroll
        for (int mt = 0; mt < 4; ++mt)
          wf[mt] = (kt < 4) ? pf2[kt][mt] : wfrag(wp + W_ENC2, kt, 4 * wv + mt);
#pragma unroll
        for (int mt = 0; mt < 4; ++mt)
#pragma unroll
          for (int rt = 0; rt < 4; ++rt) acc[mt][rt] = MFMA(wf[mt], hf[rt], acc[mt][rt]);
      }
      // prefetch the FULL q-tile-0 of W_ATTN (consumed after B3)
#pragma unroll
      for (int k2 = 0; k2 < 8; ++k2) {
        pfq[k2][0] = wfrag(wp + W_ATTN, k2, 0);
        pfq[k2][1] = wfrag(wp + W_ATTN, k2, 1);
      }
      BAR();  // B2: all h1 reads done
#pragma unroll
      for (int mt = 0; mt < 4; ++mt) {
        f32x4 bv4 = *(const f32x4*)(b_enc2 + 64 * wv + 16 * mt + 4 * g);
#pragma unroll
        for (int rt = 0; rt < 4; ++rt) {
          half4_t hv;
#pragma unroll
          for (int r = 0; r < 4; ++r) hv[r] = (_Float16)fmaxf(acc[mt][rt][r] + bv4[r], 0.f);
          stT(mt, rt, hv);
        }
      }
    }
    BAR();  // B3: emb visible
    // ===== P3+P4: scoresT = emb @ qT (q dbuf-pipelined), softmax =====
    {
      half8 aeK[8];
#pragma unroll
      for (int k2 = 0; k2 < 8; ++k2) aeK[k2] = ldA(R0, k2, wv);
      f32x4 sc[4]{};
      {
        f32x4 q2[2]{};
#pragma unroll
        for (int k2 = 0; k2 < 8; ++k2) {
          q2[0] = MFMA(aeK[k2], pfq[k2][0], q2[0]);
          q2[1] = MFMA(aeK[k2], pfq[k2][1], q2[1]);
        }
        stQ(q2, 0);
      }
#pragma unroll
      for (int ktp = 0; ktp < 8; ++ktp) {
        f32x4 q2n[2]{};
        if (ktp < 7) {  // compute next q chunk BEFORE the wall
#pragma unroll
          for (int k2 = 0; k2 < 8; ++k2) {
            q2n[0] = MFMA(aeK[k2], wfrag(wp + W_ATTN, k2, 2 * ktp + 2), q2n[0]);
            q2n[1] = MFMA(aeK[k2], wfrag(wp + W_ATTN, k2, 2 * ktp + 3), q2n[1]);
          }
        }
        asm volatile("s_waitcnt lgkmcnt(0)" ::: "memory");
        half8 qb = *(const half8*)(ATTp + (8 + 2 * wv + (ktp & 1)) * 512 + lane * 8);
        if (ktp < 7) stQ(q2n, (ktp + 1) & 1);
#pragma unroll
        for (int rt = 0; rt < 4; ++rt) sc[rt] = MFMA(ldA(R0, ktp, rt), qb, sc[rt]);
      }
      // softmax over row (16wv+c), spread across lanes {g*16+c}
      float m = sc[0][0];
#pragma unroll
      for (int rt = 0; rt < 4; ++rt)
#pragma unroll
        for (int r = 0; r < 4; ++r) m = fmaxf(m, sc[rt][r]);
      m = fmaxf(m, __shfl_xor(m, 16));
      m = fmaxf(m, __shfl_xor(m, 32));
      float e[4][4], s = 0.f;
#pragma unroll
      for (int rt = 0; rt < 4; ++rt)
#pragma unroll
        for (int r = 0; r < 4; ++r) {
          e[rt][r] = __expf(sc[rt][r] - m);
          s += e[rt][r];
        }
      s += __shfl_xor(s, 16);
      s += __shfl_xor(s, 32);
      float inv = 1.0f / s;
      // prefetch P5's kt=0,1 weights (consumed after B4)
#pragma unroll
      for (int s5 = 0; s5 < 2; ++s5)
#pragma unroll
        for (int nt = 0; nt < 4; ++nt) {
          pf5g[s5][nt] = wfrag(wp + W_GC1, s5, 4 * wv + nt);
          pf5n[s5][nt] = wfrag(wp + W_NN1, s5, 4 * wv + nt);
        }
      float* ao = attn_out + ((size_t)bb * NA + 16 * wv + c) * NA;
#pragma unroll
      for (int rt = 0; rt < 4; ++rt) {
        f32x4 vv;
        half4_t hh;
#pragma unroll
        for (int r = 0; r < 4; ++r) {
          vv[r] = e[rt][r] * inv;
          hh[r] = (_Float16)vv[r];
        }
        *(f32x4*)(ao + 16 * rt + 4 * g) = vv;
        int fi = (rt >> 1) * 4 + wv;
        int lanep = (2 * (rt & 1) + (g >> 1)) * 16 + c;
        *(half4_t*)(ATTp + fi * 512 + lanep * 8 + 4 * (g & 1)) = hh;
      }
    }
    BAR();  // B4: emb reads done; ATT frags 0..7 complete
    // ===== P5 fused pass over x (LDS): xg1 = x@gc1+b (normal);
    //        nn1T = relu((x@nn1)^T + b) via swapped MFMA -> regs =====
    half4_t r1h[4][4];  // [nt][rt]: transposed nn1 branch
    {
      f32x4 aG[4][4]{}, aN[4][4]{};  // aN indexed [nt][rt]
#pragma unroll
      for (int kt = 0; kt < 4; ++kt) {
        half8 af[4], b1[4], b2[4];
#pragma unroll
        for (int rt = 0; rt < 4; ++rt) af[rt] = ldA(X, kt, rt);
#pragma unroll
        for (int nt = 0; nt < 4; ++nt)
          b1[nt] = (kt < 2) ? pf5g[kt][nt] : wfrag(wp + W_GC1, kt, 4 * wv + nt);
#pragma unroll
        for (int nt = 0; nt < 4; ++nt)
          b2[nt] = (kt < 2) ? pf5n[kt][nt] : wfrag(wp + W_NN1, kt, 4 * wv + nt);
#pragma unroll
        for (int rt = 0; rt < 4; ++rt)
#pragma unroll
          for (int nt = 0; nt < 4; ++nt) {
            aG[rt][nt] = MFMA(af[rt], b1[nt], aG[rt][nt]);
            aN[nt][rt] = MFMA(b2[nt], af[rt], aN[nt][rt]);  // (x@nn1)^T tile
          }
      }
      ep_storeB(aG, b_gc1);  // xg1 -> R0 (own frags; consumed by same wave in P6)
#pragma unroll
      for (int nt = 0; nt < 4; ++nt) {
        f32x4 bv4 = *(const f32x4*)(b_nn1 + 64 * wv + 16 * nt + 4 * g);
#pragma unroll
        for (int rt = 0; rt < 4; ++rt)
#pragma unroll
          for (int r = 0; r < 4; ++r)
            r1h[nt][rt][r] = (_Float16)fmaxf(aN[nt][rt][r] + bv4[r], 0.f);
      }
      // prefetch P7's kt=0,1 weights (consumed after B7)
#pragma unroll
      for (int s2 = 0; s2 < 2; ++s2)
#pragma unroll
        for (int nt = 0; nt < 4; ++nt) {
          pf7n[s2][nt] = wfrag(wp + W_NN2, s2, 4 * wv + nt);
          pf7g[s2][nt] = wfrag(wp + W_GC2, s2, 4 * wv + nt);
        }
    }
    // (B5 removed: xg1 producer == consumer wave)
    // ===== P6: featT = ((relu(attn@xg1)+nn1)/64)^T -> sigma slots (half4) =====
    {
      // prefetch P7's kt=2 weights (hides under mm_att)
#pragma unroll
      for (int nt = 0; nt < 4; ++nt) {
        pf7n[2][nt] = wfrag(wp + W_NN2, 2, 4 * wv + nt);
        pf7g[2][nt] = wfrag(wp + W_GC2, 2, 4 * wv + nt);
      }
      f32x4 a1[4][4]{};  // [nt][rt]: (attn@xg1)^T tiles
#pragma unroll
      for (int kt = 0; kt < 2; ++kt) {
        half8 af[4], bf[4];
#pragma unroll
        for (int rt = 0; rt < 4; ++rt) af[rt] = ldA(ATTp, kt, rt);
#pragma unroll
        for (int nt = 0; nt < 4; ++nt) bf[nt] = ldB(R0, kt, 4 * wv + nt);
#pragma unroll
        for (int rt = 0; rt < 4; ++rt)
#pragma unroll
          for (int nt = 0; nt < 4; ++nt) a1[nt][rt] = MFMA(bf[nt], af[rt], a1[nt][rt]);
      }
      // (B6 removed: sigma slots == this wave's own xg1-read frags)
#pragma unroll
      for (int nt = 0; nt < 4; ++nt)
#pragma unroll
        for (int rt = 0; rt < 4; ++rt) {
          half4_t hv;
#pragma unroll
          for (int r = 0; r < 4; ++r)
            hv[r] = (_Float16)((fmaxf(a1[nt][rt][r], 0.f) + (float)r1h[nt][rt][r]) *
                               0.015625f);
          stFeatT(nt, rt, hv);
        }
    }
    BAR();  // B7: feat (sigma) visible to all waves
    // --- cross-batch x prefetch: stage next element's x into X (dead after P5).
    //     Ordered before next P1's reads by B8 (full lgkm-drain barrier). ---
    if (it == 0) {
      const float* xn = x + (size_t)(bb0 + 1) * (NA * SA);
#pragma unroll
      for (int rt = 0; rt < 4; ++rt) {
        half8 h = xfrag(xn, 16 * rt, wv * 32);
        *(half8*)(X + (wv * 4 + rt) * 512 + lane * 8) = h;
      }
    }
    // ===== P7 fused pass over feat: nn2T -> regs (swapped); fg2 = feat@gc2+b =====
    half4_t r2h[4][4];  // [nt][rt]: transposed nn2 branch
    {
      f32x4 aN2[4][4]{}, aG2[4][4]{};  // aN2 indexed [nt][rt]
#pragma unroll
      for (int kt = 0; kt < 8; ++kt) {
        half8 af[4], b1[4], b2[4];
#pragma unroll
        for (int rt = 0; rt < 4; ++rt) af[rt] = ldFeat(kt, rt);
#pragma unroll
        for (int nt = 0; nt < 4; ++nt)
          b1[nt] = (kt < 3) ? pf7n[kt][nt] : wfrag(wp + W_NN2, kt, 4 * wv + nt);
#pragma unroll
        for (int nt = 0; nt < 4; ++nt)
          b2[nt] = (kt < 3) ? pf7g[kt][nt] : wfrag(wp + W_GC2, kt, 4 * wv + nt);
#pragma unroll
        for (int rt = 0; rt < 4; ++rt)
#pragma unroll
          for (int nt = 0; nt < 4; ++nt) {
            aN2[nt][rt] = MFMA(b1[nt], af[rt], aN2[nt][rt]);  // (feat@nn2)^T
            aG2[rt][nt] = MFMA(af[rt], b2[nt], aG2[rt][nt]);
          }
      }
#pragma unroll
      for (int nt = 0; nt < 4; ++nt) {
        f32x4 bv4 = *(const f32x4*)(b_nn2 + 64 * wv + 16 * nt + 4 * g);
#pragma unroll
        for (int rt = 0; rt < 4; ++rt)
#pragma unroll
          for (int r = 0; r < 4; ++r)
            r2h[nt][rt][r] = (_Float16)fmaxf(aN2[nt][rt][r] + bv4[r], 0.f);
      }
      BAR();  // B8: all feat reads done (fg2 overwrites sigma slots); X staged
      ep_storeB(aG2, b_gc2);  // fg2 -> R0 (own frags; consumed by same wave in P8)
    }
    // (B9 removed: fg2 producer == consumer wave)
    // ===== P8: outT = ((relu(attn@fg2)+nn2)/64)^T -> global f32x4 =====
    {
      f32x4 a1[4][4]{};  // [nt][rt]
#pragma unroll
      for (int kt = 0; kt < 2; ++kt) {
        half8 af[4], bf[4];
#pragma unroll
        for (int rt = 0; rt < 4; ++rt) af[rt] = ldA(ATTp, kt, rt);
#pragma unroll
        for (int nt = 0; nt < 4; ++nt) bf[nt] = ldB(R0, kt, 4 * wv + nt);
#pragma unroll
        for (int rt = 0; rt < 4; ++rt)
#pragma unroll
          for (int nt = 0; nt < 4; ++nt) a1[nt][rt] = MFMA(bf[nt], af[rt], a1[nt][rt]);
      }
      float* ob = out + (size_t)bb * NA * HID;
#pragma unroll
      for (int nt = 0; nt < 4; ++nt)
#pragma unroll
        for (int rt = 0; rt < 4; ++rt) {
          f32x4 vv;
#pragma unroll
          for (int r = 0; r < 4; ++r)
            vv[r] = (fmaxf(a1[nt][rt][r], 0.f) + (float)r2h[nt][rt][r]) * 0.015625f;
          // lane holds out[row=16rt+c][col=64wv+16nt+4g+r], r contiguous
          *(f32x4*)(ob + (size_t)(16 * rt + c) * HID + 64 * wv + 16 * nt + 4 * g) = vv;
        }
    }
  }
}

extern "C" void kernel_launch(void* const* d_in, const int* in_sizes, int n_in,
                              void* d_out, int out_size, void* d_ws, size_t ws_size,
                              hipStream_t stream) {
  const float* x = (const float*)d_in[0];
  const float* enc_w1 = (const float*)d_in[1];
  const float* enc_b1 = (const float*)d_in[2];
  const float* enc_w2 = (const float*)d_in[3];
  const float* enc_b2 = (const float*)d_in[4];
  const float* attn_w = (const float*)d_in[5];
  const float* gc1_w = (const float*)d_in[6];
  const float* gc1_b = (const float*)d_in[7];
  const float* nn1_w = (const float*)d_in[8];
  const float* nn1_b = (const float*)d_in[9];
  const float* gc2_w = (const float*)d_in[10];
  const float* gc2_b = (const float*)d_in[11];
  const float* nn2_w = (const float*)d_in[12];
  const float* nn2_b = (const float*)d_in[13];
  // d_in[14] = n_agents (=64, compile-time constant)

  _Float16* wp = (_Float16*)d_ws;
  float* out = (float*)d_out;
  float* attn_o = out + (size_t)NBATCH * NA * HID;

  pack_all<<<176, 256, 0, stream>>>(enc_w1, enc_w2, attn_w, gc1_w, nn1_w, gc2_w,
                                    nn2_w, wp);
  dicg_main<<<NBATCH / 2, 256, SMEM_BYTES, stream>>>(
      x, enc_b1, enc_b2, gc1_b, nn1_b, gc2_b, nn2_b, wp, out, attn_o);
}

// Round 17
// 218.592 us; speedup vs baseline: 3.6803x; 3.6803x over previous
//
#include <hip/hip_runtime.h>

typedef _Float16 half8 __attribute__((ext_vector_type(8)));
typedef _Float16 half4_t __attribute__((ext_vector_type(4)));
typedef float f32x4 __attribute__((ext_vector_type(4)));

#define NBATCH 2048
#define NA 64
#define SA 128
#define HID 256

// LDS halves: X 8192 (16KB) | R0 16384 (32KB) | ATT 8192 (16KB) = 65536 B
// ATT frags 0..7: attn A-frags; frags 8..15: per-wave q double-buffer slots.
#define OFF_X 0
#define OFF_R0 8192
#define OFF_ATT (8192 + 16384)
#define SMEM_BYTES ((8192 + 16384 + 8192) * 2)

// packed fp16 weight offsets (halves) inside d_ws
#define W_ENC1 0
#define W_ENC2 (W_ENC1 + 128 * 256)
#define W_ATTN (W_ENC2 + 256 * 256)
#define W_GC1 (W_ATTN + 256 * 256)
#define W_NN1 (W_GC1 + 128 * 256)
#define W_GC2 (W_NN1 + 128 * 256)
#define W_NN2 (W_GC2 + 256 * 256)

#define MFMA(a, b, cacc) __builtin_amdgcn_mfma_f32_16x16x32_f16((a), (b), (cacc), 0, 0, 0)
// T5: boost wave priority for MFMA bursts (pays with 2 independent blocks/CU
// at uncorrelated phases — m191-like regime).
#define PRIO1() __builtin_amdgcn_s_setprio(1)
#define PRIO0() __builtin_amdgcn_s_setprio(0)

// lgkmcnt-only barrier. All cross-wave dataflow at these barriers is through
// LDS (lgkm-counted). __syncthreads would also drain vmcnt(0), killing any
// in-flight global weight prefetch; this keeps it alive across the barrier.
#define BAR()                                            \
  do {                                                   \
    asm volatile("s_waitcnt lgkmcnt(0)" ::: "memory");   \
    __builtin_amdgcn_s_barrier();                        \
  } while (0)

// One launch packs all 7 weights into MFMA B-fragment order fp16.
// dst[((kt*16+nt)*64+lane)*8 + j] = W[kt*32 + (lane>>4)*8 + j][nt*16 + (lane&15)]
__global__ void pack_all(const float* __restrict__ e1, const float* __restrict__ e2,
                         const float* __restrict__ aw, const float* __restrict__ g1,
                         const float* __restrict__ n1, const float* __restrict__ g2,
                         const float* __restrict__ n2, _Float16* __restrict__ dst) {
  int b = (int)blockIdx.x;
  const float* src;
  int off;
  if (b < 16) { src = e1; off = W_ENC1; }
  else if (b < 48) { src = e2; off = W_ENC2; b -= 16; }
  else if (b < 80) { src = aw; off = W_ATTN; b -= 48; }
  else if (b < 96) { src = g1; off = W_GC1; b -= 80; }
  else if (b < 112) { src = n1; off = W_NN1; b -= 96; }
  else if (b < 144) { src = g2; off = W_GC2; b -= 112; }
  else { src = n2; off = W_NN2; b -= 144; }
  int t = b * 256 + (int)threadIdx.x;
  int lane = t & 63, frag = t >> 6;
  int nt = frag & 15, kt = frag >> 4;
  int g = lane >> 4, c = lane & 15;
  half8 h;
#pragma unroll
  for (int j = 0; j < 8; ++j)
    h[j] = (_Float16)src[(size_t)(kt * 32 + g * 8 + j) * 256 + nt * 16 + c];
  *(half8*)(dst + off + (size_t)t * 8) = h;
}

__global__ __launch_bounds__(256, 2) void dicg_main(
    const float* __restrict__ x, const float* __restrict__ b_enc1,
    const float* __restrict__ b_enc2, const float* __restrict__ b_gc1,
    const float* __restrict__ b_nn1, const float* __restrict__ b_gc2,
    const float* __restrict__ b_nn2, const _Float16* __restrict__ wp,
    float* __restrict__ out, float* __restrict__ attn_out) {
  extern __shared__ _Float16 sm[];
  _Float16* X = sm + OFF_X;        // x fp16 A-frags (written P1, read P5)
  _Float16* R0 = sm + OFF_R0;      // h1 -> emb -> xg1T -> feat -> fg2T
  _Float16* ATTp = sm + OFF_ATT;   // frags 0..7: attn A-frags; 8..15: q dbuf

  const int tid = (int)threadIdx.x;
  const int wv = tid >> 6;   // wave 0..3 (owns output cols 64*wv..+63)
  const int lane = tid & 63;
  const int g = lane >> 4;   // 0..3
  const int c = lane & 15;   // 0..15
  const int bb = (int)blockIdx.x;
  const float* __restrict__ xb = x + (size_t)bb * (NA * SA);

  // ---- fragment-linear LDS loads (conflict-free: lane*16B contiguous) ----
  auto ldA = [&](const _Float16* p, int kt, int rt) -> half8 {
    return *(const half8*)(p + (kt * 4 + rt) * 512 + lane * 8);
  };
  auto ldB = [&](const _Float16* p, int kt, int ct) -> half8 {
    return *(const half8*)(p + (kt * 16 + ct) * 512 + lane * 8);
  };
  auto wfrag = [&](const _Float16* wb, int kt, int ntg) -> half8 {
    return *(const half8*)(wb + ((size_t)(kt * 16 + ntg) * 64 + lane) * 8);
  };
  auto xfrag = [&](int r0, int k0) -> half8 {
    const float* p = xb + (r0 + c) * SA + k0 + g * 8;
    f32x4 u = *(const f32x4*)p;
    f32x4 v = *(const f32x4*)(p + 4);
    half8 h;
    h[0] = (_Float16)u[0]; h[1] = (_Float16)u[1];
    h[2] = (_Float16)u[2]; h[3] = (_Float16)u[3];
    h[4] = (_Float16)v[0]; h[5] = (_Float16)v[1];
    h[6] = (_Float16)v[2]; h[7] = (_Float16)v[3];
    return h;
  };

  // ---- C-layout -> packed-LDS stores ----
  // producer lane holds D[16rt+4g+r][64wv+16nt+c]
  auto stA_val = [&](_Float16* dst, int rt, int nt, int r, float v) {
    int kt = 2 * wv + (nt >> 1);
    int lanep = (2 * (nt & 1) + (c >> 3)) * 16 + 4 * g + r;
    dst[(kt * 4 + rt) * 512 + lanep * 8 + (c & 7)] = (_Float16)v;
  };
  auto ep_storeA = [&](f32x4(&acc)[4][4], const float* bias, bool dorelu) {
#pragma unroll
    for (int nt = 0; nt < 4; ++nt) {
      float bv = bias[64 * wv + 16 * nt + c];
#pragma unroll
      for (int rt = 0; rt < 4; ++rt)
#pragma unroll
        for (int r = 0; r < 4; ++r) {
          float y = acc[rt][nt][r] + bv;
          if (dorelu) y = fmaxf(y, 0.f);
          stA_val(R0, rt, nt, r, y);
        }
    }
  };
  // B-packed store, vectorized: 4 consecutive halves per (rt,nt)
  auto ep_storeB = [&](f32x4(&acc)[4][4], const float* bias) {
#pragma unroll
    for (int nt = 0; nt < 4; ++nt) {
      float bv = bias[64 * wv + 16 * nt + c];
#pragma unroll
      for (int rt = 0; rt < 4; ++rt) {
        half4_t h;
#pragma unroll
        for (int r = 0; r < 4; ++r) h[r] = (_Float16)(acc[rt][nt][r] + bv);
        int fi = (rt >> 1) * 16 + 4 * wv + nt;
        int lanep = (2 * (rt & 1) + (g >> 1)) * 16 + c;
        *(half4_t*)(R0 + fi * 512 + lanep * 8 + 4 * (g & 1)) = h;
      }
    }
  };
  // q chunk C-layout -> per-wave double-buffered B-frag scratch (frags 8..15)
  auto stQ = [&](const f32x4(&q2)[2], int s) {
    _Float16* base = ATTp + (8 + 2 * wv + s) * 512;
#pragma unroll
    for (int nt2 = 0; nt2 < 2; ++nt2)
#pragma unroll
      for (int r = 0; r < 4; ++r)
        base[((2 * nt2 + (c >> 3)) * 16 + 4 * g + r) * 8 + (c & 7)] = (_Float16)q2[nt2][r];
  };
  auto mm_att = [&](f32x4(&acc)[4][4]) {
#pragma unroll
    for (int kt = 0; kt < 2; ++kt) {
      half8 af[4], bf[4];
#pragma unroll
      for (int rt = 0; rt < 4; ++rt) af[rt] = ldA(ATTp, kt, rt);
#pragma unroll
      for (int nt = 0; nt < 4; ++nt) bf[nt] = ldB(R0, kt, 4 * wv + nt);
      PRIO1();
#pragma unroll
      for (int rt = 0; rt < 4; ++rt)
#pragma unroll
        for (int nt = 0; nt < 4; ++nt) acc[rt][nt] = MFMA(af[rt], bf[nt], acc[rt][nt]);
      PRIO0();
    }
  };

  // cross-barrier weight prefetch registers
  half8 pf2[4][4];               // P2: W_ENC2 kt=0..3
  half8 pfq[8][2];               // P3: W_ATTN k2=0..7, cols 0,1 (full q-tile 0)
  half8 pf5g[2][4], pf5n[2][4];  // P5: W_GC1 / W_NN1 kt=0,1
  half8 pf7n[3][4], pf7g[3][4];  // P7: W_NN2 / W_GC2 kt=0,1 (P5) + kt=2 (P6)

  // ========== P1: h1 = relu(x@enc1+b1) -> R0; stage x fp16 frags -> X ==========
  {
    f32x4 acc[4][4]{};
#pragma unroll
    for (int kt = 0; kt < 4; ++kt) {
      half8 af[4], bf[4];
#pragma unroll
      for (int rt = 0; rt < 4; ++rt) af[rt] = xfrag(16 * rt, kt * 32);
#pragma unroll
      for (int nt = 0; nt < 4; ++nt) bf[nt] = wfrag(wp + W_ENC1, kt, 4 * wv + nt);
      if (kt == wv) {  // each wave stages one kt of x
#pragma unroll
        for (int rt = 0; rt < 4; ++rt)
          *(half8*)(X + (kt * 4 + rt) * 512 + lane * 8) = af[rt];
      }
      PRIO1();
#pragma unroll
      for (int rt = 0; rt < 4; ++rt)
#pragma unroll
        for (int nt = 0; nt < 4; ++nt) acc[rt][nt] = MFMA(af[rt], bf[nt], acc[rt][nt]);
      PRIO0();
    }
    // prefetch P2's first four K-tiles of W_ENC2 (consumed after B1)
#pragma unroll
    for (int s = 0; s < 4; ++s)
#pragma unroll
      for (int nt = 0; nt < 4; ++nt) pf2[s][nt] = wfrag(wp + W_ENC2, s, 4 * wv + nt);
    ep_storeA(acc, b_enc1, true);
  }
  BAR();  // B1
  // ========== P2: emb = relu(h1@enc2+b2), in-place ==========
  {
    f32x4 acc[4][4]{};
#pragma unroll
    for (int kt = 0; kt < 8; ++kt) {
      half8 af[4], bf[4];
#pragma unroll
      for (int rt = 0; rt < 4; ++rt) af[rt] = ldA(R0, kt, rt);
#pragma unroll
      for (int nt = 0; nt < 4; ++nt)
        bf[nt] = (kt < 4) ? pf2[kt][nt] : wfrag(wp + W_ENC2, kt, 4 * wv + nt);
      PRIO1();
#pragma unroll
      for (int rt = 0; rt < 4; ++rt)
#pragma unroll
        for (int nt = 0; nt < 4; ++nt) acc[rt][nt] = MFMA(af[rt], bf[nt], acc[rt][nt]);
      PRIO0();
    }
    // prefetch the FULL q-tile-0 of W_ATTN (consumed after B3)
#pragma unroll
    for (int k2 = 0; k2 < 8; ++k2) {
      pfq[k2][0] = wfrag(wp + W_ATTN, k2, 0);
      pfq[k2][1] = wfrag(wp + W_ATTN, k2, 1);
    }
    BAR();  // B2: all h1 reads done
    ep_storeA(acc, b_enc2, true);
  }
  BAR();  // B3
  // ===== P3+P4: scoresT = emb @ qT (q dbuf-pipelined), softmax =====
  {
    half8 aeK[8];
#pragma unroll
    for (int k2 = 0; k2 < 8; ++k2) aeK[k2] = ldA(R0, k2, wv);
    f32x4 sc[4]{};
    {
      f32x4 q2[2]{};
      PRIO1();
#pragma unroll
      for (int k2 = 0; k2 < 8; ++k2) {
        q2[0] = MFMA(aeK[k2], pfq[k2][0], q2[0]);
        q2[1] = MFMA(aeK[k2], pfq[k2][1], q2[1]);
      }
      PRIO0();
      stQ(q2, 0);
    }
#pragma unroll
    for (int ktp = 0; ktp < 8; ++ktp) {
      f32x4 q2n[2]{};
      if (ktp < 7) {  // compute next q chunk BEFORE the wall
        PRIO1();
#pragma unroll
        for (int k2 = 0; k2 < 8; ++k2) {
          q2n[0] = MFMA(aeK[k2], wfrag(wp + W_ATTN, k2, 2 * ktp + 2), q2n[0]);
          q2n[1] = MFMA(aeK[k2], wfrag(wp + W_ATTN, k2, 2 * ktp + 3), q2n[1]);
        }
        PRIO0();
      }
      asm volatile("s_waitcnt lgkmcnt(0)" ::: "memory");
      half8 qb = *(const half8*)(ATTp + (8 + 2 * wv + (ktp & 1)) * 512 + lane * 8);
      if (ktp < 7) stQ(q2n, (ktp + 1) & 1);
      PRIO1();
#pragma unroll
      for (int rt = 0; rt < 4; ++rt) sc[rt] = MFMA(ldA(R0, ktp, rt), qb, sc[rt]);
      PRIO0();
    }
    // softmax over row (16wv+c), spread across lanes {g*16+c}
    float m = sc[0][0];
#pragma unroll
    for (int rt = 0; rt < 4; ++rt)
#pragma unroll
      for (int r = 0; r < 4; ++r) m = fmaxf(m, sc[rt][r]);
    m = fmaxf(m, __shfl_xor(m, 16));
    m = fmaxf(m, __shfl_xor(m, 32));
    float e[4][4], s = 0.f;
#pragma unroll
    for (int rt = 0; rt < 4; ++rt)
#pragma unroll
      for (int r = 0; r < 4; ++r) {
        e[rt][r] = __expf(sc[rt][r] - m);
        s += e[rt][r];
      }
    s += __shfl_xor(s, 16);
    s += __shfl_xor(s, 32);
    float inv = 1.0f / s;
    // prefetch P5's kt=0,1 weights (consumed after B4)
#pragma unroll
    for (int s5 = 0; s5 < 2; ++s5)
#pragma unroll
      for (int nt = 0; nt < 4; ++nt) {
        pf5g[s5][nt] = wfrag(wp + W_GC1, s5, 4 * wv + nt);
        pf5n[s5][nt] = wfrag(wp + W_NN1, s5, 4 * wv + nt);
      }
    float* ao = attn_out + ((size_t)bb * NA + 16 * wv + c) * NA;
#pragma unroll
    for (int rt = 0; rt < 4; ++rt) {
      f32x4 vv;
      half4_t hh;
#pragma unroll
      for (int r = 0; r < 4; ++r) {
        vv[r] = e[rt][r] * inv;
        hh[r] = (_Float16)vv[r];
      }
      *(f32x4*)(ao + 16 * rt + 4 * g) = vv;
      int fi = (rt >> 1) * 4 + wv;
      int lanep = (2 * (rt & 1) + (g >> 1)) * 16 + c;
      *(half4_t*)(ATTp + fi * 512 + lanep * 8 + 4 * (g & 1)) = hh;
    }
  }
  BAR();  // B4: emb reads done; ATT frags 0..7 complete
  // ===== P5 fused pass over x (LDS): xg1 = x@gc1+b; nn1 = relu(x@nn1+b) =====
  half4_t r1h[4][4];
  {
    f32x4 aG[4][4]{}, aN[4][4]{};
#pragma unroll
    for (int kt = 0; kt < 4; ++kt) {
      half8 af[4], b1[4], b2[4];
#pragma unroll
      for (int rt = 0; rt < 4; ++rt) af[rt] = ldA(X, kt, rt);
#pragma unroll
      for (int nt = 0; nt < 4; ++nt)
        b1[nt] = (kt < 2) ? pf5g[kt][nt] : wfrag(wp + W_GC1, kt, 4 * wv + nt);
#pragma unroll
      for (int nt = 0; nt < 4; ++nt)
        b2[nt] = (kt < 2) ? pf5n[kt][nt] : wfrag(wp + W_NN1, kt, 4 * wv + nt);
      PRIO1();
#pragma unroll
      for (int rt = 0; rt < 4; ++rt)
#pragma unroll
        for (int nt = 0; nt < 4; ++nt) {
          aG[rt][nt] = MFMA(af[rt], b1[nt], aG[rt][nt]);
          aN[rt][nt] = MFMA(af[rt], b2[nt], aN[rt][nt]);
        }
      PRIO0();
    }
    ep_storeB(aG, b_gc1);  // xg1 -> R0 (over emb; safe after B4)
#pragma unroll
    for (int nt = 0; nt < 4; ++nt) {
      float bv = b_nn1[64 * wv + 16 * nt + c];
#pragma unroll
      for (int rt = 0; rt < 4; ++rt)
#pragma unroll
        for (int r = 0; r < 4; ++r)
          r1h[rt][nt][r] = (_Float16)fmaxf(aN[rt][nt][r] + bv, 0.f);
    }
    // prefetch P7's kt=0,1 weights (consumed after B7)
#pragma unroll
    for (int s2 = 0; s2 < 2; ++s2)
#pragma unroll
      for (int nt = 0; nt < 4; ++nt) {
        pf7n[s2][nt] = wfrag(wp + W_NN2, s2, 4 * wv + nt);
        pf7g[s2][nt] = wfrag(wp + W_GC2, s2, 4 * wv + nt);
      }
  }
  BAR();  // B5: xg1 visible to all waves
  // ===== P6: feat = (relu(attn@xg1) + nn1)/64 -> R0 =====
  {
    // prefetch P7's kt=2 weights (hides under mm_att + B6/B7 barriers)
#pragma unroll
    for (int nt = 0; nt < 4; ++nt) {
      pf7n[2][nt] = wfrag(wp + W_NN2, 2, 4 * wv + nt);
      pf7g[2][nt] = wfrag(wp + W_GC2, 2, 4 * wv + nt);
    }
    f32x4 a1[4][4]{};
    mm_att(a1);
    BAR();  // B6: all xg1 reads done
#pragma unroll
    for (int nt = 0; nt < 4; ++nt)
#pragma unroll
      for (int rt = 0; rt < 4; ++rt)
#pragma unroll
        for (int r = 0; r < 4; ++r)
          stA_val(R0, rt, nt, r,
                  (fmaxf(a1[rt][nt][r], 0.f) + (float)r1h[rt][nt][r]) * 0.015625f);
  }
  BAR();  // B7: feat complete
  // ===== P7 fused pass over feat: nn2 -> regs; fg2 = feat@gc2+b -> R0 =====
  half4_t r2h[4][4];
  {
    f32x4 aN2[4][4]{}, aG2[4][4]{};
#pragma unroll
    for (int kt = 0; kt < 8; ++kt) {
      half8 af[4], b1[4], b2[4];
#pragma unroll
      for (int rt = 0; rt < 4; ++rt) af[rt] = ldA(R0, kt, rt);
#pragma unroll
      for (int nt = 0; nt < 4; ++nt)
        b1[nt] = (kt < 3) ? pf7n[kt][nt] : wfrag(wp + W_NN2, kt, 4 * wv + nt);
#pragma unroll
      for (int nt = 0; nt < 4; ++nt)
        b2[nt] = (kt < 3) ? pf7g[kt][nt] : wfrag(wp + W_GC2, kt, 4 * wv + nt);
      PRIO1();
#pragma unroll
      for (int rt = 0; rt < 4; ++rt)
#pragma unroll
        for (int nt = 0; nt < 4; ++nt) {
          aN2[rt][nt] = MFMA(af[rt], b1[nt], aN2[rt][nt]);
          aG2[rt][nt] = MFMA(af[rt], b2[nt], aG2[rt][nt]);
        }
      PRIO0();
    }
#pragma unroll
    for (int nt = 0; nt < 4; ++nt) {
      float bv = b_nn2[64 * wv + 16 * nt + c];
#pragma unroll
      for (int rt = 0; rt < 4; ++rt)
#pragma unroll
        for (int r = 0; r < 4; ++r)
          r2h[rt][nt][r] = (_Float16)fmaxf(aN2[rt][nt][r] + bv, 0.f);
    }
    BAR();  // B8: all feat reads done
    ep_storeB(aG2, b_gc2);  // fg2 -> R0
  }
  BAR();  // B9
  // ===== P8: out = (relu(attn@fg2) + nn2)/64 -> global =====
  {
    f32x4 a1[4][4]{};
    mm_att(a1);
    float* ob = out + (size_t)bb * NA * HID;
#pragma unroll
    for (int nt = 0; nt < 4; ++nt)
#pragma unroll
      for (int rt = 0; rt < 4; ++rt)
#pragma unroll
        for (int r = 0; r < 4; ++r)
          ob[(size_t)(16 * rt + 4 * g + r) * HID + 64 * wv + 16 * nt + c] =
              (fmaxf(a1[rt][nt][r], 0.f) + (float)r2h[rt][nt][r]) * 0.015625f;
  }
}

extern "C" void kernel_launch(void* const* d_in, const int* in_sizes, int n_in,
                              void* d_out, int out_size, void* d_ws, size_t ws_size,
                              hipStream_t stream) {
  const float* x = (const float*)d_in[0];
  const float* enc_w1 = (const float*)d_in[1];
  const float* enc_b1 = (const float*)d_in[2];
  const float* enc_w2 = (const float*)d_in[3];
  const float* enc_b2 = (const float*)d_in[4];
  const float* attn_w = (const float*)d_in[5];
  const float* gc1_w = (const float*)d_in[6];
  const float* gc1_b = (const float*)d_in[7];
  const float* nn1_w = (const float*)d_in[8];
  const float* nn1_b = (const float*)d_in[9];
  const float* gc2_w = (const float*)d_in[10];
  const float* gc2_b = (const float*)d_in[11];
  const float* nn2_w = (const float*)d_in[12];
  const float* nn2_b = (const float*)d_in[13];
  // d_in[14] = n_agents (=64, compile-time constant)

  _Float16* wp = (_Float16*)d_ws;
  float* out = (float*)d_out;
  float* attn_o = out + (size_t)NBATCH * NA * HID;

  pack_all<<<176, 256, 0, stream>>>(enc_w1, enc_w2, attn_w, gc1_w, nn1_w, gc2_w,
                                    nn2_w, wp);
  dicg_main<<<NBATCH, 256, SMEM_BYTES, stream>>>(
      x, enc_b1, enc_b2, gc1_b, nn1_b, gc2_b, nn2_b, wp, out, attn_o);
}

// Round 18
// 154.302 us; speedup vs baseline: 5.2137x; 1.4166x over previous
//
#include <hip/hip_runtime.h>

typedef _Float16 half8 __attribute__((ext_vector_type(8)));
typedef _Float16 half4_t __attribute__((ext_vector_type(4)));
typedef float f32x4 __attribute__((ext_vector_type(4)));

#define NBATCH 2048
#define NA 64
#define SA 128
#define HID 256

// LDS halves: X 8192 (16KB) | R0 16384 (32KB) | ATT 8192 (16KB) = 65536 B
// ATT frags 0..7: attn A-frags; frags 8..15: per-wave q double-buffer slots.
#define OFF_X 0
#define OFF_R0 8192
#define OFF_ATT (8192 + 16384)
#define SMEM_BYTES ((8192 + 16384 + 8192) * 2)

// packed fp16 weight offsets (halves) inside d_ws
#define W_ENC1 0
#define W_ENC2 (W_ENC1 + 128 * 256)
#define W_ATTN (W_ENC2 + 256 * 256)
#define W_GC1 (W_ATTN + 256 * 256)
#define W_NN1 (W_GC1 + 128 * 256)
#define W_GC2 (W_NN1 + 128 * 256)
#define W_NN2 (W_GC2 + 256 * 256)

#define MFMA(a, b, cacc) __builtin_amdgcn_mfma_f32_16x16x32_f16((a), (b), (cacc), 0, 0, 0)

// lgkmcnt-only barrier. All cross-wave dataflow at these barriers is through
// LDS (lgkm-counted). __syncthreads would also drain vmcnt(0), killing any
// in-flight global weight prefetch; this keeps it alive across the barrier.
#define BAR()                                            \
  do {                                                   \
    asm volatile("s_waitcnt lgkmcnt(0)" ::: "memory");   \
    __builtin_amdgcn_s_barrier();                        \
  } while (0)

// One launch packs all 7 weights into MFMA B-fragment order fp16.
// dst[((kt*16+nt)*64+lane)*8 + j] = W[kt*32 + (lane>>4)*8 + j][nt*16 + (lane&15)]
__global__ void pack_all(const float* __restrict__ e1, const float* __restrict__ e2,
                         const float* __restrict__ aw, const float* __restrict__ g1,
                         const float* __restrict__ n1, const float* __restrict__ g2,
                         const float* __restrict__ n2, _Float16* __restrict__ dst) {
  int b = (int)blockIdx.x;
  const float* src;
  int off;
  if (b < 16) { src = e1; off = W_ENC1; }
  else if (b < 48) { src = e2; off = W_ENC2; b -= 16; }
  else if (b < 80) { src = aw; off = W_ATTN; b -= 48; }
  else if (b < 96) { src = g1; off = W_GC1; b -= 80; }
  else if (b < 112) { src = n1; off = W_NN1; b -= 96; }
  else if (b < 144) { src = g2; off = W_GC2; b -= 112; }
  else { src = n2; off = W_NN2; b -= 144; }
  int t = b * 256 + (int)threadIdx.x;
  int lane = t & 63, frag = t >> 6;
  int nt = frag & 15, kt = frag >> 4;
  int g = lane >> 4, c = lane & 15;
  half8 h;
#pragma unroll
  for (int j = 0; j < 8; ++j)
    h[j] = (_Float16)src[(size_t)(kt * 32 + g * 8 + j) * 256 + nt * 16 + c];
  *(half8*)(dst + off + (size_t)t * 8) = h;
}

__global__ __launch_bounds__(256, 2) void dicg_main(
    const float* __restrict__ x, const float* __restrict__ b_enc1,
    const float* __restrict__ b_enc2, const float* __restrict__ b_gc1,
    const float* __restrict__ b_nn1, const float* __restrict__ b_gc2,
    const float* __restrict__ b_nn2, const _Float16* __restrict__ wp,
    float* __restrict__ out, float* __restrict__ attn_out) {
  extern __shared__ _Float16 sm[];
  _Float16* X = sm + OFF_X;        // x fp16 A-frags (written P1, read P5)
  _Float16* R0 = sm + OFF_R0;      // h1 -> emb -> xg1T -> feat -> fg2T
  _Float16* ATTp = sm + OFF_ATT;   // frags 0..7: attn A-frags; 8..15: q dbuf

  const int tid = (int)threadIdx.x;
  const int wv = tid >> 6;   // wave 0..3 (owns output cols 64*wv..+63)
  const int lane = tid & 63;
  const int g = lane >> 4;   // 0..3
  const int c = lane & 15;   // 0..15
  const int bb = (int)blockIdx.x;
  const float* __restrict__ xb = x + (size_t)bb * (NA * SA);

  // ---- fragment-linear LDS loads (conflict-free: lane*16B contiguous) ----
  auto ldA = [&](const _Float16* p, int kt, int rt) -> half8 {
    return *(const half8*)(p + (kt * 4 + rt) * 512 + lane * 8);
  };
  auto ldB = [&](const _Float16* p, int kt, int ct) -> half8 {
    return *(const half8*)(p + (kt * 16 + ct) * 512 + lane * 8);
  };
  auto wfrag = [&](const _Float16* wb, int kt, int ntg) -> half8 {
    return *(const half8*)(wb + ((size_t)(kt * 16 + ntg) * 64 + lane) * 8);
  };
  auto xfrag = [&](int r0, int k0) -> half8 {
    const float* p = xb + (r0 + c) * SA + k0 + g * 8;
    f32x4 u = *(const f32x4*)p;
    f32x4 v = *(const f32x4*)(p + 4);
    half8 h;
    h[0] = (_Float16)u[0]; h[1] = (_Float16)u[1];
    h[2] = (_Float16)u[2]; h[3] = (_Float16)u[3];
    h[4] = (_Float16)v[0]; h[5] = (_Float16)v[1];
    h[6] = (_Float16)v[2]; h[7] = (_Float16)v[3];
    return h;
  };

  // ---- C-layout -> packed-LDS stores ----
  // producer lane holds D[16rt+4g+r][64wv+16nt+c]
  auto stA_val = [&](_Float16* dst, int rt, int nt, int r, float v) {
    int kt = 2 * wv + (nt >> 1);
    int lanep = (2 * (nt & 1) + (c >> 3)) * 16 + 4 * g + r;
    dst[(kt * 4 + rt) * 512 + lanep * 8 + (c & 7)] = (_Float16)v;
  };
  auto ep_storeA = [&](f32x4(&acc)[4][4], const float* bias, bool dorelu) {
#pragma unroll
    for (int nt = 0; nt < 4; ++nt) {
      float bv = bias[64 * wv + 16 * nt + c];
#pragma unroll
      for (int rt = 0; rt < 4; ++rt)
#pragma unroll
        for (int r = 0; r < 4; ++r) {
          float y = acc[rt][nt][r] + bv;
          if (dorelu) y = fmaxf(y, 0.f);
          stA_val(R0, rt, nt, r, y);
        }
    }
  };
  // B-packed store, vectorized: 4 consecutive halves per (rt,nt)
  auto ep_storeB = [&](f32x4(&acc)[4][4], const float* bias) {
#pragma unroll
    for (int nt = 0; nt < 4; ++nt) {
      float bv = bias[64 * wv + 16 * nt + c];
#pragma unroll
      for (int rt = 0; rt < 4; ++rt) {
        half4_t h;
#pragma unroll
        for (int r = 0; r < 4; ++r) h[r] = (_Float16)(acc[rt][nt][r] + bv);
        int fi = (rt >> 1) * 16 + 4 * wv + nt;
        int lanep = (2 * (rt & 1) + (g >> 1)) * 16 + c;
        *(half4_t*)(R0 + fi * 512 + lanep * 8 + 4 * (g & 1)) = h;
      }
    }
  };
  // q chunk C-layout -> per-wave double-buffered B-frag scratch (frags 8..15)
  auto stQ = [&](const f32x4(&q2)[2], int s) {
    _Float16* base = ATTp + (8 + 2 * wv + s) * 512;
#pragma unroll
    for (int nt2 = 0; nt2 < 2; ++nt2)
#pragma unroll
      for (int r = 0; r < 4; ++r)
        base[((2 * nt2 + (c >> 3)) * 16 + 4 * g + r) * 8 + (c & 7)] = (_Float16)q2[nt2][r];
  };
  auto mm_att = [&](f32x4(&acc)[4][4]) {
#pragma unroll
    for (int kt = 0; kt < 2; ++kt) {
      half8 af[4], bf[4];
#pragma unroll
      for (int rt = 0; rt < 4; ++rt) af[rt] = ldA(ATTp, kt, rt);
#pragma unroll
      for (int nt = 0; nt < 4; ++nt) bf[nt] = ldB(R0, kt, 4 * wv + nt);
#pragma unroll
      for (int rt = 0; rt < 4; ++rt)
#pragma unroll
        for (int nt = 0; nt < 4; ++nt) acc[rt][nt] = MFMA(af[rt], bf[nt], acc[rt][nt]);
    }
  };

  // cross-barrier weight prefetch registers
  half8 pf2[4][4];               // P2: W_ENC2 kt=0..3
  half8 pfq[8][2];               // P3: W_ATTN k2=0..7, cols 0,1 (full q-tile 0)
  half8 pf5g[2][4], pf5n[2][4];  // P5: W_GC1 / W_NN1 kt=0,1
  half8 pf7n[3][4], pf7g[3][4];  // P7: W_NN2 / W_GC2 kt=0,1 (P5) + kt=2 (P6)

  // ========== P1: h1 = relu(x@enc1+b1) -> R0; stage x fp16 frags -> X ==========
  {
    f32x4 acc[4][4]{};
#pragma unroll
    for (int kt = 0; kt < 4; ++kt) {
      half8 af[4], bf[4];
#pragma unroll
      for (int rt = 0; rt < 4; ++rt) af[rt] = xfrag(16 * rt, kt * 32);
#pragma unroll
      for (int nt = 0; nt < 4; ++nt) bf[nt] = wfrag(wp + W_ENC1, kt, 4 * wv + nt);
      if (kt == wv) {  // each wave stages one kt of x
#pragma unroll
        for (int rt = 0; rt < 4; ++rt)
          *(half8*)(X + (kt * 4 + rt) * 512 + lane * 8) = af[rt];
      }
#pragma unroll
      for (int rt = 0; rt < 4; ++rt)
#pragma unroll
        for (int nt = 0; nt < 4; ++nt) acc[rt][nt] = MFMA(af[rt], bf[nt], acc[rt][nt]);
    }
    // prefetch P2's first four K-tiles of W_ENC2 (consumed after B1)
#pragma unroll
    for (int s = 0; s < 4; ++s)
#pragma unroll
      for (int nt = 0; nt < 4; ++nt) pf2[s][nt] = wfrag(wp + W_ENC2, s, 4 * wv + nt);
    ep_storeA(acc, b_enc1, true);
  }
  BAR();  // B1
  // ========== P2: emb = relu(h1@enc2+b2), in-place ==========
  {
    f32x4 acc[4][4]{};
#pragma unroll
    for (int kt = 0; kt < 8; ++kt) {
      half8 af[4], bf[4];
#pragma unroll
      for (int rt = 0; rt < 4; ++rt) af[rt] = ldA(R0, kt, rt);
#pragma unroll
      for (int nt = 0; nt < 4; ++nt)
        bf[nt] = (kt < 4) ? pf2[kt][nt] : wfrag(wp + W_ENC2, kt, 4 * wv + nt);
#pragma unroll
      for (int rt = 0; rt < 4; ++rt)
#pragma unroll
        for (int nt = 0; nt < 4; ++nt) acc[rt][nt] = MFMA(af[rt], bf[nt], acc[rt][nt]);
    }
    // prefetch the FULL q-tile-0 of W_ATTN (consumed after B3)
#pragma unroll
    for (int k2 = 0; k2 < 8; ++k2) {
      pfq[k2][0] = wfrag(wp + W_ATTN, k2, 0);
      pfq[k2][1] = wfrag(wp + W_ATTN, k2, 1);
    }
    BAR();  // B2: all h1 reads done
    ep_storeA(acc, b_enc2, true);
  }
  BAR();  // B3
  // ===== P3+P4: scoresT = emb @ qT (q dbuf-pipelined), softmax =====
  {
    half8 aeK[8];
#pragma unroll
    for (int k2 = 0; k2 < 8; ++k2) aeK[k2] = ldA(R0, k2, wv);
    f32x4 sc[4]{};
    {
      f32x4 q2[2]{};
#pragma unroll
      for (int k2 = 0; k2 < 8; ++k2) {
        q2[0] = MFMA(aeK[k2], pfq[k2][0], q2[0]);
        q2[1] = MFMA(aeK[k2], pfq[k2][1], q2[1]);
      }
      stQ(q2, 0);
    }
#pragma unroll
    for (int ktp = 0; ktp < 8; ++ktp) {
      f32x4 q2n[2]{};
      if (ktp < 7) {  // compute next q chunk BEFORE the wall
#pragma unroll
        for (int k2 = 0; k2 < 8; ++k2) {
          q2n[0] = MFMA(aeK[k2], wfrag(wp + W_ATTN, k2, 2 * ktp + 2), q2n[0]);
          q2n[1] = MFMA(aeK[k2], wfrag(wp + W_ATTN, k2, 2 * ktp + 3), q2n[1]);
        }
      }
      asm volatile("s_waitcnt lgkmcnt(0)" ::: "memory");
      half8 qb = *(const half8*)(ATTp + (8 + 2 * wv + (ktp & 1)) * 512 + lane * 8);
      if (ktp < 7) stQ(q2n, (ktp + 1) & 1);
#pragma unroll
      for (int rt = 0; rt < 4; ++rt) sc[rt] = MFMA(ldA(R0, ktp, rt), qb, sc[rt]);
    }
    // softmax over row (16wv+c), spread across lanes {g*16+c}
    float m = sc[0][0];
#pragma unroll
    for (int rt = 0; rt < 4; ++rt)
#pragma unroll
      for (int r = 0; r < 4; ++r) m = fmaxf(m, sc[rt][r]);
    m = fmaxf(m, __shfl_xor(m, 16));
    m = fmaxf(m, __shfl_xor(m, 32));
    float e[4][4], s = 0.f;
#pragma unroll
    for (int rt = 0; rt < 4; ++rt)
#pragma unroll
      for (int r = 0; r < 4; ++r) {
        e[rt][r] = __expf(sc[rt][r] - m);
        s += e[rt][r];
      }
    s += __shfl_xor(s, 16);
    s += __shfl_xor(s, 32);
    float inv = 1.0f / s;
    // prefetch P5's kt=0,1 weights (consumed after B4)
#pragma unroll
    for (int s5 = 0; s5 < 2; ++s5)
#pragma unroll
      for (int nt = 0; nt < 4; ++nt) {
        pf5g[s5][nt] = wfrag(wp + W_GC1, s5, 4 * wv + nt);
        pf5n[s5][nt] = wfrag(wp + W_NN1, s5, 4 * wv + nt);
      }
    float* ao = attn_out + ((size_t)bb * NA + 16 * wv + c) * NA;
#pragma unroll
    for (int rt = 0; rt < 4; ++rt) {
      f32x4 vv;
      half4_t hh;
#pragma unroll
      for (int r = 0; r < 4; ++r) {
        vv[r] = e[rt][r] * inv;
        hh[r] = (_Float16)vv[r];
      }
      *(f32x4*)(ao + 16 * rt + 4 * g) = vv;
      int fi = (rt >> 1) * 4 + wv;
      int lanep = (2 * (rt & 1) + (g >> 1)) * 16 + c;
      *(half4_t*)(ATTp + fi * 512 + lanep * 8 + 4 * (g & 1)) = hh;
    }
  }
  BAR();  // B4: emb reads done; ATT frags 0..7 complete
  // ===== P5 fused pass over x (LDS): xg1 = x@gc1+b; nn1 = relu(x@nn1+b) =====
  half4_t r1h[4][4];
  {
    f32x4 aG[4][4]{}, aN[4][4]{};
#pragma unroll
    for (int kt = 0; kt < 4; ++kt) {
      half8 af[4], b1[4], b2[4];
#pragma unroll
      for (int rt = 0; rt < 4; ++rt) af[rt] = ldA(X, kt, rt);
#pragma unroll
      for (int nt = 0; nt < 4; ++nt)
        b1[nt] = (kt < 2) ? pf5g[kt][nt] : wfrag(wp + W_GC1, kt, 4 * wv + nt);
#pragma unroll
      for (int nt = 0; nt < 4; ++nt)
        b2[nt] = (kt < 2) ? pf5n[kt][nt] : wfrag(wp + W_NN1, kt, 4 * wv + nt);
#pragma unroll
      for (int rt = 0; rt < 4; ++rt)
#pragma unroll
        for (int nt = 0; nt < 4; ++nt) {
          aG[rt][nt] = MFMA(af[rt], b1[nt], aG[rt][nt]);
          aN[rt][nt] = MFMA(af[rt], b2[nt], aN[rt][nt]);
        }
    }
    ep_storeB(aG, b_gc1);  // xg1 -> R0 (over emb; safe after B4)
#pragma unroll
    for (int nt = 0; nt < 4; ++nt) {
      float bv = b_nn1[64 * wv + 16 * nt + c];
#pragma unroll
      for (int rt = 0; rt < 4; ++rt)
#pragma unroll
        for (int r = 0; r < 4; ++r)
          r1h[rt][nt][r] = (_Float16)fmaxf(aN[rt][nt][r] + bv, 0.f);
    }
    // prefetch P7's kt=0,1 weights (consumed after B7)
#pragma unroll
    for (int s2 = 0; s2 < 2; ++s2)
#pragma unroll
      for (int nt = 0; nt < 4; ++nt) {
        pf7n[s2][nt] = wfrag(wp + W_NN2, s2, 4 * wv + nt);
        pf7g[s2][nt] = wfrag(wp + W_GC2, s2, 4 * wv + nt);
      }
  }
  BAR();  // B5: xg1 visible to all waves
  // ===== P6: feat = (relu(attn@xg1) + nn1)/64 -> R0 =====
  {
    // prefetch P7's kt=2 weights (hides under mm_att + B6/B7 barriers)
#pragma unroll
    for (int nt = 0; nt < 4; ++nt) {
      pf7n[2][nt] = wfrag(wp + W_NN2, 2, 4 * wv + nt);
      pf7g[2][nt] = wfrag(wp + W_GC2, 2, 4 * wv + nt);
    }
    f32x4 a1[4][4]{};
    mm_att(a1);
    BAR();  // B6: all xg1 reads done
#pragma unroll
    for (int nt = 0; nt < 4; ++nt)
#pragma unroll
      for (int rt = 0; rt < 4; ++rt)
#pragma unroll
        for (int r = 0; r < 4; ++r)
          stA_val(R0, rt, nt, r,
                  (fmaxf(a1[rt][nt][r], 0.f) + (float)r1h[rt][nt][r]) * 0.015625f);
  }
  BAR();  // B7: feat complete
  // ===== P7 fused pass over feat: nn2 -> regs; fg2 = feat@gc2+b -> R0 =====
  half4_t r2h[4][4];
  {
    f32x4 aN2[4][4]{}, aG2[4][4]{};
#pragma unroll
    for (int kt = 0; kt < 8; ++kt) {
      half8 af[4], b1[4], b2[4];
#pragma unroll
      for (int rt = 0; rt < 4; ++rt) af[rt] = ldA(R0, kt, rt);
#pragma unroll
      for (int nt = 0; nt < 4; ++nt)
        b1[nt] = (kt < 3) ? pf7n[kt][nt] : wfrag(wp + W_NN2, kt, 4 * wv + nt);
#pragma unroll
      for (int nt = 0; nt < 4; ++nt)
        b2[nt] = (kt < 3) ? pf7g[kt][nt] : wfrag(wp + W_GC2, kt, 4 * wv + nt);
#pragma unroll
      for (int rt = 0; rt < 4; ++rt)
#pragma unroll
        for (int nt = 0; nt < 4; ++nt) {
          aN2[rt][nt] = MFMA(af[rt], b1[nt], aN2[rt][nt]);
          aG2[rt][nt] = MFMA(af[rt], b2[nt], aG2[rt][nt]);
        }
    }
#pragma unroll
    for (int nt = 0; nt < 4; ++nt) {
      float bv = b_nn2[64 * wv + 16 * nt + c];
#pragma unroll
      for (int rt = 0; rt < 4; ++rt)
#pragma unroll
        for (int r = 0; r < 4; ++r)
          r2h[rt][nt][r] = (_Float16)fmaxf(aN2[rt][nt][r] + bv, 0.f);
    }
    BAR();  // B8: all feat reads done
    ep_storeB(aG2, b_gc2);  // fg2 -> R0
  }
  BAR();  // B9
  // ===== P8: out = (relu(attn@fg2) + nn2)/64 -> global =====
  {
    f32x4 a1[4][4]{};
    mm_att(a1);
    float* ob = out + (size_t)bb * NA * HID;
#pragma unroll
    for (int nt = 0; nt < 4; ++nt)
#pragma unroll
      for (int rt = 0; rt < 4; ++rt)
#pragma unroll
        for (int r = 0; r < 4; ++r)
          ob[(size_t)(16 * rt + 4 * g + r) * HID + 64 * wv + 16 * nt + c] =
              (fmaxf(a1[rt][nt][r], 0.f) + (float)r2h[rt][nt][r]) * 0.015625f;
  }
}

extern "C" void kernel_launch(void* const* d_in, const int* in_sizes, int n_in,
                              void* d_out, int out_size, void* d_ws, size_t ws_size,
                              hipStream_t stream) {
  const float* x = (const float*)d_in[0];
  const float* enc_w1 = (const float*)d_in[1];
  const float* enc_b1 = (const float*)d_in[2];
  const float* enc_w2 = (const float*)d_in[3];
  const float* enc_b2 = (const float*)d_in[4];
  const float* attn_w = (const float*)d_in[5];
  const float* gc1_w = (const float*)d_in[6];
  const float* gc1_b = (const float*)d_in[7];
  const float* nn1_w = (const float*)d_in[8];
  const float* nn1_b = (const float*)d_in[9];
  const float* gc2_w = (const float*)d_in[10];
  const float* gc2_b = (const float*)d_in[11];
  const float* nn2_w = (const float*)d_in[12];
  const float* nn2_b = (const float*)d_in[13];
  // d_in[14] = n_agents (=64, compile-time constant)

  _Float16* wp = (_Float16*)d_ws;
  float* out = (float*)d_out;
  float* attn_o = out + (size_t)NBATCH * NA * HID;

  pack_all<<<176, 256, 0, stream>>>(enc_w1, enc_w2, attn_w, gc1_w, nn1_w, gc2_w,
                                    nn2_w, wp);
  dicg_main<<<NBATCH, 256, SMEM_BYTES, stream>>>(
      x, enc_b1, enc_b2, gc1_b, nn1_b, gc2_b, nn2_b, wp, out, attn_o);
}